// Round 8
// baseline (228.116 us; speedup 1.0000x reference)
//
#include <hip/hip_runtime.h>
#include <hip/hip_bf16.h>

// Problem constants
#define N_    8192
#define K_    200
#define CIN_  512
#define HID_  256
#define COUT_ 40
#define E_    5
#define MH_   64
#define KG_   40
#define EPS_  1e-5f

// Workspace layout (floats):
#define WS_VSUM  0
#define WS_BNSUM 256
#define WS_T     768
#define WS_S     103168
#define WS_G     103424

typedef __bf16 bf16x8 __attribute__((ext_vector_type(8)));
typedef _Float16 f16x2 __attribute__((ext_vector_type(2)));
typedef _Float16 f16x8 __attribute__((ext_vector_type(8)));
typedef float  f32x16 __attribute__((ext_vector_type(16)));

__device__ __forceinline__ uint packbf(float a, float b) {
    union { __bf16 h[2]; uint u; } p;
    p.h[0] = (__bf16)a; p.h[1] = (__bf16)b;
    return p.u;
}

union UB { uint4 q; bf16x8 v; };
union UHF { f16x2 h2[4]; f16x8 v; };

// ---------------------------------------------------------------------------
// Expert MLP via MFMA.  v4: fp16 packed math for the B-fragment build
// (one v_pk_fma_f16 + v_pk_max_f16 per 2 elements via native f16x2 vectors),
// f16 MFMA (same fragment layout family as the verified bf16 path),
// U loads hoisted with incremental n/kg.
// ---------------------------------------------------------------------------
__global__ __launch_bounds__(256) void k_expert(
    const float* __restrict__ U,
    const float* __restrict__ eW1, const float* __restrict__ eb1,
    const float* __restrict__ eW2, const float* __restrict__ eb2,
    const float* __restrict__ eW3, const float* __restrict__ eb3,
    float* __restrict__ Vsum)
{
    const int e   = blockIdx.x;
    const int tid = threadIdx.x;
    const int w   = tid >> 6;        // wave 0..3
    const int l   = tid & 63;        // lane
    const int lo  = l & 31;
    const int hi  = l >> 5;

    __shared__ f16x2 sW1h[32], sb1h[32];
    __shared__ float sb2s[MH_], sW3s[MH_];
    __shared__ float colsum[KG_];

    if (tid < 32) {
        f16x2 w2; w2.x = (_Float16)eW1[e*MH_ + 2*tid]; w2.y = (_Float16)eW1[e*MH_ + 2*tid + 1];
        sW1h[tid] = w2;
        f16x2 b2; b2.x = (_Float16)eb1[e*MH_ + 2*tid]; b2.y = (_Float16)eb1[e*MH_ + 2*tid + 1];
        sb1h[tid] = b2;
    }
    if (tid < MH_) {
        sb2s[tid] = eb2[e*MH_ + tid];
        sW3s[tid] = eW3[e*MH_ + tid];
    }
    if (tid < KG_) colsum[tid] = 0.f;
    const float b3 = eb3[e];

    // A fragments (W2^T) in fp16, 8 frags x 4 VGPRs.
    UHF fa[2][4];
    {
        const float* W2e = eW2 + e*MH_*MH_;
        #pragma unroll
        for (int mt = 0; mt < 2; ++mt) {
            const int grow = mt*32 + lo;
            #pragma unroll
            for (int t = 0; t < 4; ++t) {
                const int k0 = 16*t + 8*hi;
                #pragma unroll
                for (int r = 0; r < 4; ++r) {
                    f16x2 p;
                    p.x = (_Float16)W2e[(k0+2*r  )*MH_ + grow];
                    p.y = (_Float16)W2e[(k0+2*r+1)*MH_ + grow];
                    fa[mt][t].h2[r] = p;
                }
            }
        }
    }
    __syncthreads();

    // hoisted U loads: elem idx for it = base0 + it*256; n/kg incremental
    float uu[4]; int kgs[4];
    {
        const int idx0 = (blockIdx.y*16 + w)*64 + l;
        int n = idx0 / KG_, kg = idx0 - n*KG_;
        #pragma unroll
        for (int it = 0; it < 4; ++it) {
            uu[it]  = U[n*K_ + e*KG_ + kg];
            kgs[it] = kg;
            kg += 16; if (kg >= KG_) { kg -= KG_; n += 1; }
            n += 6;
        }
    }

    const f16x2 z2 = {(_Float16)0.f, (_Float16)0.f};

    #pragma unroll
    for (int it = 0; it < 4; ++it) {
        const float ucol0 = __shfl(uu[it], lo);
        const float ucol1 = __shfl(uu[it], 32 + lo);
        f16x2 u20; u20.x = (_Float16)ucol0; u20.y = (_Float16)ucol0;
        f16x2 u21; u21.x = (_Float16)ucol1; u21.y = (_Float16)ucol1;

        f32x16 acc00 = {0}; f32x16 acc10 = {0};
        f32x16 acc01 = {0}; f32x16 acc11 = {0};
        #pragma unroll
        for (int t = 0; t < 4; ++t) {
            const int kp = 8*t + 4*hi;       // f16x2 index of k0 = 16t+8hi
            UHF b0, b1;
            #pragma unroll
            for (int r = 0; r < 4; ++r) {
                const f16x2 w1  = sW1h[kp + r];
                const f16x2 b1c = sb1h[kp + r];
                b0.h2[r] = __builtin_elementwise_max(u20*w1 + b1c, z2);
                b1.h2[r] = __builtin_elementwise_max(u21*w1 + b1c, z2);
            }
            acc00 = __builtin_amdgcn_mfma_f32_32x32x16_f16(fa[0][t].v, b0.v, acc00, 0, 0, 0);
            acc10 = __builtin_amdgcn_mfma_f32_32x32x16_f16(fa[1][t].v, b0.v, acc10, 0, 0, 0);
            acc01 = __builtin_amdgcn_mfma_f32_32x32x16_f16(fa[0][t].v, b1.v, acc01, 0, 0, 0);
            acc11 = __builtin_amdgcn_mfma_f32_32x32x16_f16(fa[1][t].v, b1.v, acc11, 0, 0, 0);
        }

        float vs0 = 0.f, vs1 = 0.f;
        #pragma unroll
        for (int r = 0; r < 16; ++r) {
            const int gb  = (r & 3) + 8*(r >> 2) + 4*hi;
            const float b2a = sb2s[gb],      w3a = sW3s[gb];
            const float b2b = sb2s[32 + gb], w3b = sW3s[32 + gb];
            vs0 += fmaxf(acc00[r] + b2a, 0.f)*w3a + fmaxf(acc10[r] + b2b, 0.f)*w3b;
            vs1 += fmaxf(acc01[r] + b2a, 0.f)*w3a + fmaxf(acc11[r] + b2b, 0.f)*w3b;
        }
        vs0 += __shfl_xor(vs0, 32);
        vs1 += __shfl_xor(vs1, 32);

        const float myv = (hi ? vs1 : vs0) + b3;
        atomicAdd(&colsum[kgs[it]], myv);
    }

    __syncthreads();
    if (tid < KG_) atomicAdd(&Vsum[e*KG_ + tid], colsum[tid]);
}

// ---------------------------------------------------------------------------
// Gate (unchanged)
// ---------------------------------------------------------------------------
__global__ void k_gate(
    const float* __restrict__ La,
    const float* __restrict__ gW1, const float* __restrict__ gb1,
    const float* __restrict__ gW2, const float* __restrict__ gb2,
    const float* __restrict__ Vsum, float* __restrict__ s)
{
    __shared__ float sg[E_];
    const int tid = threadIdx.x;
    if (tid == 0) {
        float stats[E_], g1[E_], g2[E_];
        for (int e = 0; e < E_; ++e) {
            float acc = 0.f;
            for (int k = 0; k < KG_; ++k) acc += La[e*KG_ + k];
            stats[e] = acc * (1.0f/KG_);
        }
        for (int j = 0; j < E_; ++j) {
            float acc = gb1[j];
            for (int i = 0; i < E_; ++i) acc += stats[i]*gW1[i*E_ + j];
            g1[j] = fmaxf(acc, 0.f);
        }
        float m = -1e30f;
        for (int j = 0; j < E_; ++j) {
            float acc = gb2[j];
            for (int i = 0; i < E_; ++i) acc += g1[i]*gW2[i*E_ + j];
            g2[j] = acc;
            m = fmaxf(m, acc);
        }
        float ssum = 0.f;
        for (int j = 0; j < E_; ++j) { g2[j] = expf(g2[j]-m); ssum += g2[j]; }
        for (int j = 0; j < E_; ++j) sg[j] = g2[j] / ssum;
    }
    __syncthreads();
    if (tid < K_) s[tid] = sg[tid / KG_] * Vsum[tid] * (1.0f/N_);
}

// ---------------------------------------------------------------------------
// P[ks] = partial of T = U^T X via MFMA.  v5: 2-phase pipelined.
// Block: 64M x 64N tile, K-range 512 rows as 8 chunks of 64, double-buffered
// pair-packed LDS [rp][col] (uint4 writes, pad 68).  Per chunk: issue next
// chunk's 8 float4 loads, compute current (32 ds_read_b32 + 4 MFMA/wave),
// pack+write next, ONE barrier.  No atomics: partials to P (d_out scratch).
// grid (8 nblk, 4 mblk, 16 ks) = 512 blocks; 4 waves = 2x2 quadrants.
// Frag conv (verified): reg r <-> k-rows 16ksi+8hi+2r(+1); C/D col=lane&31,
// row = (r&3)+8*(r>>2)+4*hi.
// ---------------------------------------------------------------------------
__global__ __launch_bounds__(256) void k_utx(
    const float* __restrict__ U, const float* __restrict__ X,
    float* __restrict__ P)
{
    const int nc0 = blockIdx.x * 64;
    const int mc0 = blockIdx.y * 64;
    const int ks  = blockIdx.z;
    const int r0  = ks * 512;
    const int tid = threadIdx.x;
    const int w   = tid >> 6, l = tid & 63, lo = l & 31, hi = l >> 5;
    const int mq  = w >> 1, nq = w & 1;

    __shared__ uint sU[2][32][68];   // 17.4 KB
    __shared__ uint sX[2][32][68];   // 17.4 KB

    const int rpA = tid >> 4;        // 0..15
    const int rpB = rpA + 16;
    const int c4  = tid & 15;
    const int mcA = mc0 + 4*c4;      // may exceed 199 for mblk=3 -> clamp addr
    const int xcA = nc0 + 4*c4;
    const int UMAX = N_*K_ - 4;

    float4 uA0,uA1,uB0,uB1,xA0,xA1,xB0,xB1;

#define UTX_LD(chunk) {                                                       \
    const int rb_ = r0 + 64*(chunk);                                          \
    uA0 = *reinterpret_cast<const float4*>(&U[min((rb_+2*rpA  )*K_ + mcA, UMAX)]); \
    uA1 = *reinterpret_cast<const float4*>(&U[min((rb_+2*rpA+1)*K_ + mcA, UMAX)]); \
    uB0 = *reinterpret_cast<const float4*>(&U[min((rb_+2*rpB  )*K_ + mcA, UMAX)]); \
    uB1 = *reinterpret_cast<const float4*>(&U[min((rb_+2*rpB+1)*K_ + mcA, UMAX)]); \
    xA0 = *reinterpret_cast<const float4*>(&X[(rb_+2*rpA  )*CIN_ + xcA]);     \
    xA1 = *reinterpret_cast<const float4*>(&X[(rb_+2*rpA+1)*CIN_ + xcA]);     \
    xB0 = *reinterpret_cast<const float4*>(&X[(rb_+2*rpB  )*CIN_ + xcA]);     \
    xB1 = *reinterpret_cast<const float4*>(&X[(rb_+2*rpB+1)*CIN_ + xcA]); }

#define UTX_WR(buf) {                                                         \
    uint4 p_;                                                                 \
    p_.x = packbf(uA0.x,uA1.x); p_.y = packbf(uA0.y,uA1.y);                   \
    p_.z = packbf(uA0.z,uA1.z); p_.w = packbf(uA0.w,uA1.w);                   \
    *reinterpret_cast<uint4*>(&sU[buf][rpA][4*c4]) = p_;                      \
    p_.x = packbf(uB0.x,uB1.x); p_.y = packbf(uB0.y,uB1.y);                   \
    p_.z = packbf(uB0.z,uB1.z); p_.w = packbf(uB0.w,uB1.w);                   \
    *reinterpret_cast<uint4*>(&sU[buf][rpB][4*c4]) = p_;                      \
    p_.x = packbf(xA0.x,xA1.x); p_.y = packbf(xA0.y,xA1.y);                   \
    p_.z = packbf(xA0.z,xA1.z); p_.w = packbf(xA0.w,xA1.w);                   \
    *reinterpret_cast<uint4*>(&sX[buf][rpA][4*c4]) = p_;                      \
    p_.x = packbf(xB0.x,xB1.x); p_.y = packbf(xB0.y,xB1.y);                   \
    p_.z = packbf(xB0.z,xB1.z); p_.w = packbf(xB0.w,xB1.w);                   \
    *reinterpret_cast<uint4*>(&sX[buf][rpB][4*c4]) = p_; }

#define UTX_MM(buf) {                                                         \
    _Pragma("unroll") for (int ksi = 0; ksi < 4; ++ksi) {                     \
        const int rp0_ = 8*ksi + 4*hi;                                        \
        UB a_, b_;                                                            \
        a_.q.x = sU[buf][rp0_+0][32*mq+lo];                                   \
        a_.q.y = sU[buf][rp0_+1][32*mq+lo];                                   \
        a_.q.z = sU[buf][rp0_+2][32*mq+lo];                                   \
        a_.q.w = sU[buf][rp0_+3][32*mq+lo];                                   \
        b_.q.x = sX[buf][rp0_+0][32*nq+lo];                                   \
        b_.q.y = sX[buf][rp0_+1][32*nq+lo];                                   \
        b_.q.z = sX[buf][rp0_+2][32*nq+lo];                                   \
        b_.q.w = sX[buf][rp0_+3][32*nq+lo];                                   \
        acc = __builtin_amdgcn_mfma_f32_32x32x16_bf16(a_.v, b_.v, acc, 0,0,0); } }

    f32x16 acc = {0};
    UTX_LD(0);
    UTX_WR(0);
    __syncthreads();
    #pragma unroll
    for (int t = 0; t < 8; ++t) {
        if (t < 7) UTX_LD(t+1);          // loads fly under compute
        UTX_MM(t & 1);
        if (t < 7) UTX_WR((t+1) & 1);    // write other buffer
        __syncthreads();
    }

    #pragma unroll
    for (int r = 0; r < 16; ++r) {
        const int mrow = mc0 + mq*32 + (r & 3) + 8*(r >> 2) + 4*hi;  // 0..255
        const int ncol = nc0 + nq*32 + lo;
        P[(ks*256 + mrow)*512 + ncol] = acc[r];
    }
#undef UTX_LD
#undef UTX_WR
#undef UTX_MM
}

// ---------------------------------------------------------------------------
// T[m][c] = sum_ks P[ks][m][c], m < 200.  grid 100.
// ---------------------------------------------------------------------------
__global__ __launch_bounds__(256) void k_red(
    const float* __restrict__ P, float* __restrict__ T)
{
    const int j  = blockIdx.x*256 + threadIdx.x;  // 0..25599
    const int m  = j >> 7;                        // row (128 f4 per row)
    const int c4 = j & 127;
    float4 s4 = {0.f, 0.f, 0.f, 0.f};
    for (int ks = 0; ks < 16; ++ks) {
        const float4 v = *reinterpret_cast<const float4*>(&P[(ks*256 + m)*512 + 4*c4]);
        s4.x += v.x; s4.y += v.y; s4.z += v.z; s4.w += v.w;
    }
    *reinterpret_cast<float4*>(&T[m*512 + 4*c4]) = s4;
}

// ---------------------------------------------------------------------------
// G = T @ Ww   [200][256] (unchanged)
// ---------------------------------------------------------------------------
__global__ __launch_bounds__(256) void k_g(
    const float* __restrict__ T, const float* __restrict__ Ww,
    float* __restrict__ G)
{
    const int k0  = blockIdx.x * 4;
    const int c   = threadIdx.x;
    __shared__ float4 sT4[4][128];

    for (int j = threadIdx.x; j < 512; j += 256) {
        const int r = j >> 7, c4 = j & 127;
        sT4[r][c4] = reinterpret_cast<const float4*>(T)[(k0+r)*128 + c4];
    }
    __syncthreads();

    float a0 = 0.f, a1 = 0.f, a2 = 0.f, a3 = 0.f;
    for (int ci4 = 0; ci4 < 128; ++ci4) {
        const float w0 = Ww[(4*ci4+0)*HID_ + c];
        const float w1 = Ww[(4*ci4+1)*HID_ + c];
        const float w2 = Ww[(4*ci4+2)*HID_ + c];
        const float w3 = Ww[(4*ci4+3)*HID_ + c];
        float4 t;
        t = sT4[0][ci4]; a0 += t.x*w0 + t.y*w1 + t.z*w2 + t.w*w3;
        t = sT4[1][ci4]; a1 += t.x*w0 + t.y*w1 + t.z*w2 + t.w*w3;
        t = sT4[2][ci4]; a2 += t.x*w0 + t.y*w1 + t.z*w2 + t.w*w3;
        t = sT4[3][ci4]; a3 += t.x*w0 + t.y*w1 + t.z*w2 + t.w*w3;
    }
    G[(k0+0)*HID_ + c] = a0;
    G[(k0+1)*HID_ + c] = a1;
    G[(k0+2)*HID_ + c] = a2;
    G[(k0+3)*HID_ + c] = a3;
}

// ---------------------------------------------------------------------------
// hidden = (U*s) @ G + Wb  via MFMA + fused BN stats.  v3: 128N x 32C tiles,
// grid (8,64)=512 blocks (2/CU), pair-packed LDS [rp][col] (pad 129/33),
// 4 ds_read_b32 per fragment, 13 MFMA per wave.
// ---------------------------------------------------------------------------
__global__ __launch_bounds__(256) void k_hidden(
    const float* __restrict__ U, const float* __restrict__ s,
    const float* __restrict__ G, const float* __restrict__ Wb,
    float* __restrict__ hid, float* __restrict__ bnsum)
{
    const int c0  = blockIdx.x * 32;
    const int n0  = blockIdx.y * 128;
    const int tid = threadIdx.x;
    const int w   = tid >> 6;
    const int l   = tid & 63;
    const int lo  = l & 31;
    const int hi  = l >> 5;

    __shared__ uint  sA[104][129];   // 53.7 KB: pairs of (U*s), rows=k-pair
    __shared__ uint  sB[104][33];    // 13.7 KB: pairs of G
    __shared__ float ss[208];

    if (tid < 208) ss[tid] = (tid < K_) ? s[tid] : 0.f;
    __syncthreads();

    // stage A: unit (m 0..127, kq 0..25): k-range 8kq..8kq+7 of node n0+m
    #pragma unroll
    for (int u = 0; u < 13; ++u) {
        const int j  = tid + u*256;
        const int m  = j & 127, kq = j >> 7;
        float4 a = {0,0,0,0}, b = {0,0,0,0};
        if (kq < 25) {
            a = *reinterpret_cast<const float4*>(&U[(n0+m)*K_ + 8*kq]);
            b = *reinterpret_cast<const float4*>(&U[(n0+m)*K_ + 8*kq + 4]);
            a.x *= ss[8*kq+0]; a.y *= ss[8*kq+1]; a.z *= ss[8*kq+2]; a.w *= ss[8*kq+3];
            b.x *= ss[8*kq+4]; b.y *= ss[8*kq+5]; b.z *= ss[8*kq+6]; b.w *= ss[8*kq+7];
        }
        sA[4*kq+0][m] = packbf(a.x, a.y);
        sA[4*kq+1][m] = packbf(a.z, a.w);
        sA[4*kq+2][m] = packbf(b.x, b.y);
        sA[4*kq+3][m] = packbf(b.z, b.w);
    }
    // stage B: unit (c 0..31, kq 0..25)
    for (int j = tid; j < 832; j += 256) {
        const int c = j & 31, kq = j >> 5;
        float g[8];
        #pragma unroll
        for (int i = 0; i < 8; ++i)
            g[i] = (kq < 25) ? G[(8*kq+i)*HID_ + c0 + c] : 0.f;
        sB[4*kq+0][c] = packbf(g[0], g[1]);
        sB[4*kq+1][c] = packbf(g[2], g[3]);
        sB[4*kq+2][c] = packbf(g[4], g[5]);
        sB[4*kq+3][c] = packbf(g[6], g[7]);
    }
    __syncthreads();

    f32x16 acc = {0};
    #pragma unroll
    for (int t = 0; t < 13; ++t) {
        const int rp0 = 8*t + 4*hi;
        UB a_, b_;
        a_.q.x = sA[rp0+0][32*w + lo];
        a_.q.y = sA[rp0+1][32*w + lo];
        a_.q.z = sA[rp0+2][32*w + lo];
        a_.q.w = sA[rp0+3][32*w + lo];
        b_.q.x = sB[rp0+0][lo];
        b_.q.y = sB[rp0+1][lo];
        b_.q.z = sB[rp0+2][lo];
        b_.q.w = sB[rp0+3][lo];
        acc = __builtin_amdgcn_mfma_f32_32x32x16_bf16(a_.v, b_.v, acc, 0, 0, 0);
    }

    const float wb = Wb[c0 + lo];
    float sm = 0.f, sq = 0.f;
    #pragma unroll
    for (int r = 0; r < 16; ++r) {
        const int row = 32*w + (r & 3) + 8*(r >> 2) + 4*hi;
        const float h = acc[r] + wb;
        hid[(n0+row)*HID_ + c0 + lo] = h;
        sm += h; sq += h*h;
    }
    sm += __shfl_xor(sm, 32); sq += __shfl_xor(sq, 32);
    if (hi == 0) {
        atomicAdd(&bnsum[c0 + lo],        sm);
        atomicAdd(&bnsum[HID_ + c0 + lo], sq);
    }
}

// ---------------------------------------------------------------------------
// logits = relu(BN(hidden)) @ Mw + Mb; out = log_softmax (unchanged)
// ---------------------------------------------------------------------------
__global__ __launch_bounds__(256) void k_logits(
    const float* __restrict__ hid, const float* __restrict__ bnsum,
    const float* __restrict__ gamma, const float* __restrict__ beta,
    const float* __restrict__ Mw, const float* __restrict__ Mb,
    float* __restrict__ outls)
{
    __shared__ float sc[HID_], sh[HID_], sMb[COUT_];
    __shared__ float sMw[HID_][COUT_];        // 40 KB
    __shared__ float sPart[8][32][41];        // 42 KB

    const int tid = threadIdx.x;
    const int r   = tid & 31;
    const int sl  = tid >> 5;

    {
        const float sm = bnsum[tid], sq = bnsum[HID_+tid];
        const float mu  = sm * (1.0f/N_);
        const float var = sq * (1.0f/N_) - mu*mu;
        const float a   = gamma[tid] * rsqrtf(var + EPS_);
        sc[tid] = a;
        sh[tid] = beta[tid] - mu*a;
    }
    for (int j = tid; j < HID_*COUT_/4; j += 256)
        reinterpret_cast<float4*>(&sMw[0][0])[j] = reinterpret_cast<const float4*>(Mw)[j];
    if (tid < COUT_) sMb[tid] = Mb[tid];
    __syncthreads();

    const int n  = blockIdx.x*32 + r;
    const int cb = sl * 32;
    float acc[COUT_];
    #pragma unroll
    for (int j = 0; j < COUT_; ++j) acc[j] = 0.f;

    const float4* hrow = reinterpret_cast<const float4*>(&hid[n*HID_ + cb]);
    #pragma unroll
    for (int c4 = 0; c4 < 8; ++c4) {
        const float4 h4 = hrow[c4];
        const float hv[4] = {h4.x, h4.y, h4.z, h4.w};
        #pragma unroll
        for (int q = 0; q < 4; ++q) {
            const int c = cb + 4*c4 + q;
            const float hn = fmaxf(hv[q]*sc[c] + sh[c], 0.f);
            #pragma unroll
            for (int j0 = 0; j0 < COUT_; j0 += 4) {
                const float4 wv = *reinterpret_cast<const float4*>(&sMw[c][j0]);
                acc[j0+0] += hn*wv.x; acc[j0+1] += hn*wv.y;
                acc[j0+2] += hn*wv.z; acc[j0+3] += hn*wv.w;
            }
        }
    }
    #pragma unroll
    for (int j = 0; j < COUT_; ++j) sPart[sl][r][j] = acc[j];
    __syncthreads();

    if (tid < 32) {
        const int n2 = blockIdx.x*32 + tid;
        float a2[COUT_];
        #pragma unroll
        for (int j = 0; j < COUT_; ++j) {
            float sum = sMb[j];
            #pragma unroll
            for (int s2 = 0; s2 < 8; ++s2) sum += sPart[s2][tid][j];
            a2[j] = sum;
        }
        float m = -1e30f;
        #pragma unroll
        for (int j = 0; j < COUT_; ++j) m = fmaxf(m, a2[j]);
        float ssum = 0.f;
        #pragma unroll
        for (int j = 0; j < COUT_; ++j) ssum += expf(a2[j] - m);
        const float lse = m + logf(ssum);
        #pragma unroll
        for (int j = 0; j < COUT_; ++j)
            outls[n2*COUT_ + j] = a2[j] - lse;
    }
}

// ---------------------------------------------------------------------------
extern "C" void kernel_launch(void* const* d_in, const int* in_sizes, int n_in,
                              void* d_out, int out_size, void* d_ws, size_t ws_size,
                              hipStream_t stream)
{
    const float* X        = (const float*)d_in[0];
    const float* La       = (const float*)d_in[1];
    const float* U        = (const float*)d_in[2];
    const float* eW1      = (const float*)d_in[3];
    const float* eb1      = (const float*)d_in[4];
    const float* eW2      = (const float*)d_in[5];
    const float* eb2      = (const float*)d_in[6];
    const float* eW3      = (const float*)d_in[7];
    const float* eb3      = (const float*)d_in[8];
    const float* gW1      = (const float*)d_in[9];
    const float* gb1      = (const float*)d_in[10];
    const float* gW2      = (const float*)d_in[11];
    const float* gb2      = (const float*)d_in[12];
    const float* Ww       = (const float*)d_in[13];
    const float* Wb       = (const float*)d_in[14];
    const float* bn_gamma = (const float*)d_in[15];
    const float* bn_beta  = (const float*)d_in[16];
    const float* Mw       = (const float*)d_in[17];
    const float* Mb       = (const float*)d_in[18];

    float* out   = (float*)d_out;
    float* ws    = (float*)d_ws;
    float* Vsum  = ws + WS_VSUM;
    float* bnsum = ws + WS_BNSUM;
    float* T     = ws + WS_T;
    float* s     = ws + WS_S;
    float* G     = ws + WS_G;

    float* outls = out;                 // [8192][40] log_softmax (written last)
    float* hid   = out + N_*COUT_;      // [8192][256] hidden (output 1)
    float* P     = out;                 // k_utx partials: 16*256*512*4 = 8.4 MB
                                        // in d_out scratch, consumed by k_red
                                        // before k_hidden overwrites hid.

    // zero Vsum + bnsum (atomic accumulators); T written fully by k_red.
    (void)hipMemsetAsync(ws, 0, (size_t)768 * sizeof(float), stream);

    k_utx   <<<dim3(8, 4, 16), 256, 0, stream>>>(U, X, P);
    k_expert<<<dim3(E_, 320),  256, 0, stream>>>(U, eW1, eb1, eW2, eb2, eW3, eb3, Vsum);
    k_gate  <<<1,   256, 0, stream>>>(La, gW1, gb1, gW2, gb2, Vsum, s);
    k_red   <<<100, 256, 0, stream>>>(P, T);
    k_g     <<<50,  256, 0, stream>>>(T, Ww, G);
    k_hidden<<<dim3(8, 64), 256, 0, stream>>>(U, s, G, Wb, hid, bnsum);
    k_logits<<<256, 256, 0, stream>>>(hid, bnsum, bn_gamma, bn_beta, Mw, Mb, outls);
}

// Round 9
// 210.662 us; speedup vs baseline: 1.0829x; 1.0829x over previous
//
#include <hip/hip_runtime.h>
#include <hip/hip_bf16.h>

// Problem constants
#define N_    8192
#define K_    200
#define CIN_  512
#define HID_  256
#define COUT_ 40
#define E_    5
#define MH_   64
#define KG_   40
#define EPS_  1e-5f

// Workspace layout (floats):
#define WS_VSUM  0
#define WS_BNSUM 256
#define WS_T     768
#define WS_S     103168
#define WS_G     103424

typedef __bf16 bf16x8 __attribute__((ext_vector_type(8)));
typedef _Float16 f16x2 __attribute__((ext_vector_type(2)));
typedef _Float16 f16x8 __attribute__((ext_vector_type(8)));
typedef float  f32x16 __attribute__((ext_vector_type(16)));

__device__ __forceinline__ uint packbf(float a, float b) {
    union { __bf16 h[2]; uint u; } p;
    p.h[0] = (__bf16)a; p.h[1] = (__bf16)b;
    return p.u;
}

union UB { uint4 q; bf16x8 v; };
union UHF { f16x2 h2[4]; f16x8 v; };

// ---------------------------------------------------------------------------
// Expert MLP via MFMA.  v5: 32-col tiles (2 accs), b2 folded into MFMA C-in,
// direct per-lane U loads (no shfl), 4-way epilogue partials, per-wave
// colsum rows.  Math identical to the verified fp16 path.
// grid (E_, 640); block 256 = 4 waves; wave: 4 tiles of 32 elements.
// A (W2^T) frag: fa[mt][t].h2[r] = (W2[16t+8hi+2r][mt*32+lo], ..+1).
// B frag: b.h2[r] = (h1[col=lo][16t+8hi+2r], ..+1), h1 = relu(u*W1+b1) fp16.
// C/D: col=lane&31, row g = mt*32 + (r&3)+8*(r>>2)+4*hi (verified).
// ---------------------------------------------------------------------------
__global__ __launch_bounds__(256) void k_expert(
    const float* __restrict__ U,
    const float* __restrict__ eW1, const float* __restrict__ eb1,
    const float* __restrict__ eW2, const float* __restrict__ eb2,
    const float* __restrict__ eW3, const float* __restrict__ eb3,
    float* __restrict__ Vsum)
{
    const int e   = blockIdx.x;
    const int tid = threadIdx.x;
    const int w   = tid >> 6;        // wave 0..3
    const int l   = tid & 63;        // lane
    const int lo  = l & 31;
    const int hi  = l >> 5;

    __shared__ f16x2 sW1h[32], sb1h[32];
    __shared__ float sb2s[MH_], sW3s[MH_];
    __shared__ float colsum[4][48];  // per-wave rows, padded

    if (tid < 32) {
        f16x2 w2; w2.x = (_Float16)eW1[e*MH_ + 2*tid]; w2.y = (_Float16)eW1[e*MH_ + 2*tid + 1];
        sW1h[tid] = w2;
        f16x2 b2; b2.x = (_Float16)eb1[e*MH_ + 2*tid]; b2.y = (_Float16)eb1[e*MH_ + 2*tid + 1];
        sb1h[tid] = b2;
    }
    if (tid < MH_) {
        sb2s[tid] = eb2[e*MH_ + tid];
        sW3s[tid] = eW3[e*MH_ + tid];
    }
    if (tid < 192) colsum[tid / 48][tid % 48] = 0.f;
    const float b3 = eb3[e];

    // A fragments (W2^T) in fp16, 8 frags x 4 VGPRs.
    UHF fa[2][4];
    {
        const float* W2e = eW2 + e*MH_*MH_;
        #pragma unroll
        for (int mt = 0; mt < 2; ++mt) {
            const int grow = mt*32 + lo;
            #pragma unroll
            for (int t = 0; t < 4; ++t) {
                const int k0 = 16*t + 8*hi;
                #pragma unroll
                for (int r = 0; r < 4; ++r) {
                    f16x2 p;
                    p.x = (_Float16)W2e[(k0+2*r  )*MH_ + grow];
                    p.y = (_Float16)W2e[(k0+2*r+1)*MH_ + grow];
                    fa[mt][t].h2[r] = p;
                }
            }
        }
    }
    __syncthreads();

    // C-init registers: b2 values in the C/D layout (free b2-add via MFMA C-in)
    f32x16 ci0, ci1;
    #pragma unroll
    for (int r = 0; r < 16; ++r) {
        const int gb = (r & 3) + 8*(r >> 2) + 4*hi;
        ci0[r] = sb2s[gb];
        ci1[r] = sb2s[32 + gb];
    }

    // hoisted per-lane u loads: lane needs u of element col = lo of each tile
    float uu[4]; int kgs[4];
    const int tile0 = blockIdx.y*16 + w*4;
    #pragma unroll
    for (int it = 0; it < 4; ++it) {
        const int idx = (tile0 + it)*32 + lo;
        const int n   = idx / KG_;
        const int kg  = idx - n*KG_;
        uu[it]  = U[n*K_ + e*KG_ + kg];
        kgs[it] = kg;
    }

    const f16x2 z2 = {(_Float16)0.f, (_Float16)0.f};

    #pragma unroll
    for (int it = 0; it < 4; ++it) {
        f16x2 u2; u2.x = (_Float16)uu[it]; u2.y = u2.x;

        f32x16 a0, a1;
        #pragma unroll
        for (int t = 0; t < 4; ++t) {
            const int kp = 8*t + 4*hi;       // f16x2 index of k0 = 16t+8hi
            UHF b;
            #pragma unroll
            for (int r = 0; r < 4; ++r)
                b.h2[r] = __builtin_elementwise_max(u2*sW1h[kp + r] + sb1h[kp + r], z2);
            if (t == 0) {
                a0 = __builtin_amdgcn_mfma_f32_32x32x16_f16(fa[0][0].v, b.v, ci0, 0, 0, 0);
                a1 = __builtin_amdgcn_mfma_f32_32x32x16_f16(fa[1][0].v, b.v, ci1, 0, 0, 0);
            } else {
                a0 = __builtin_amdgcn_mfma_f32_32x32x16_f16(fa[0][t].v, b.v, a0, 0, 0, 0);
                a1 = __builtin_amdgcn_mfma_f32_32x32x16_f16(fa[1][t].v, b.v, a1, 0, 0, 0);
            }
        }

        // epilogue: v[col] = sum_g relu(D[g][col])*W3[g]; 4 partial chains
        float p0 = 0.f, p1 = 0.f, p2 = 0.f, p3 = 0.f;
        #pragma unroll
        for (int r = 0; r < 16; r += 2) {
            const int g0 = (r & 3) + 8*(r >> 2) + 4*hi;
            const int g1 = ((r+1) & 3) + 8*((r+1) >> 2) + 4*hi;
            p0 += fmaxf(a0[r],   0.f) * sW3s[g0];
            p1 += fmaxf(a1[r],   0.f) * sW3s[32 + g0];
            p2 += fmaxf(a0[r+1], 0.f) * sW3s[g1];
            p3 += fmaxf(a1[r+1], 0.f) * sW3s[32 + g1];
        }
        float vs = (p0 + p1) + (p2 + p3);
        vs += __shfl_xor(vs, 32);
        if (hi == 0) atomicAdd(&colsum[w][kgs[it]], vs + b3);
    }

    __syncthreads();
    if (tid < KG_)
        atomicAdd(&Vsum[e*KG_ + tid],
                  colsum[0][tid] + colsum[1][tid] + colsum[2][tid] + colsum[3][tid]);
}

// ---------------------------------------------------------------------------
// Gate (unchanged)
// ---------------------------------------------------------------------------
__global__ void k_gate(
    const float* __restrict__ La,
    const float* __restrict__ gW1, const float* __restrict__ gb1,
    const float* __restrict__ gW2, const float* __restrict__ gb2,
    const float* __restrict__ Vsum, float* __restrict__ s)
{
    __shared__ float sg[E_];
    const int tid = threadIdx.x;
    if (tid == 0) {
        float stats[E_], g1[E_], g2[E_];
        for (int e = 0; e < E_; ++e) {
            float acc = 0.f;
            for (int k = 0; k < KG_; ++k) acc += La[e*KG_ + k];
            stats[e] = acc * (1.0f/KG_);
        }
        for (int j = 0; j < E_; ++j) {
            float acc = gb1[j];
            for (int i = 0; i < E_; ++i) acc += stats[i]*gW1[i*E_ + j];
            g1[j] = fmaxf(acc, 0.f);
        }
        float m = -1e30f;
        for (int j = 0; j < E_; ++j) {
            float acc = gb2[j];
            for (int i = 0; i < E_; ++i) acc += g1[i]*gW2[i*E_ + j];
            g2[j] = acc;
            m = fmaxf(m, acc);
        }
        float ssum = 0.f;
        for (int j = 0; j < E_; ++j) { g2[j] = expf(g2[j]-m); ssum += g2[j]; }
        for (int j = 0; j < E_; ++j) sg[j] = g2[j] / ssum;
    }
    __syncthreads();
    if (tid < K_) s[tid] = sg[tid / KG_] * Vsum[tid] * (1.0f/N_);
}

// ---------------------------------------------------------------------------
// P[ks] = partial of T = U^T X via MFMA (2-phase pipelined, unchanged).
// ---------------------------------------------------------------------------
__global__ __launch_bounds__(256) void k_utx(
    const float* __restrict__ U, const float* __restrict__ X,
    float* __restrict__ P)
{
    const int nc0 = blockIdx.x * 64;
    const int mc0 = blockIdx.y * 64;
    const int ks  = blockIdx.z;
    const int r0  = ks * 512;
    const int tid = threadIdx.x;
    const int w   = tid >> 6, l = tid & 63, lo = l & 31, hi = l >> 5;
    const int mq  = w >> 1, nq = w & 1;

    __shared__ uint sU[2][32][68];   // 17.4 KB
    __shared__ uint sX[2][32][68];   // 17.4 KB

    const int rpA = tid >> 4;        // 0..15
    const int rpB = rpA + 16;
    const int c4  = tid & 15;
    const int mcA = mc0 + 4*c4;      // may exceed 199 for mblk=3 -> clamp addr
    const int xcA = nc0 + 4*c4;
    const int UMAX = N_*K_ - 4;

    float4 uA0,uA1,uB0,uB1,xA0,xA1,xB0,xB1;

#define UTX_LD(chunk) {                                                       \
    const int rb_ = r0 + 64*(chunk);                                          \
    uA0 = *reinterpret_cast<const float4*>(&U[min((rb_+2*rpA  )*K_ + mcA, UMAX)]); \
    uA1 = *reinterpret_cast<const float4*>(&U[min((rb_+2*rpA+1)*K_ + mcA, UMAX)]); \
    uB0 = *reinterpret_cast<const float4*>(&U[min((rb_+2*rpB  )*K_ + mcA, UMAX)]); \
    uB1 = *reinterpret_cast<const float4*>(&U[min((rb_+2*rpB+1)*K_ + mcA, UMAX)]); \
    xA0 = *reinterpret_cast<const float4*>(&X[(rb_+2*rpA  )*CIN_ + xcA]);     \
    xA1 = *reinterpret_cast<const float4*>(&X[(rb_+2*rpA+1)*CIN_ + xcA]);     \
    xB0 = *reinterpret_cast<const float4*>(&X[(rb_+2*rpB  )*CIN_ + xcA]);     \
    xB1 = *reinterpret_cast<const float4*>(&X[(rb_+2*rpB+1)*CIN_ + xcA]); }

#define UTX_WR(buf) {                                                         \
    uint4 p_;                                                                 \
    p_.x = packbf(uA0.x,uA1.x); p_.y = packbf(uA0.y,uA1.y);                   \
    p_.z = packbf(uA0.z,uA1.z); p_.w = packbf(uA0.w,uA1.w);                   \
    *reinterpret_cast<uint4*>(&sU[buf][rpA][4*c4]) = p_;                      \
    p_.x = packbf(uB0.x,uB1.x); p_.y = packbf(uB0.y,uB1.y);                   \
    p_.z = packbf(uB0.z,uB1.z); p_.w = packbf(uB0.w,uB1.w);                   \
    *reinterpret_cast<uint4*>(&sU[buf][rpB][4*c4]) = p_;                      \
    p_.x = packbf(xA0.x,xA1.x); p_.y = packbf(xA0.y,xA1.y);                   \
    p_.z = packbf(xA0.z,xA1.z); p_.w = packbf(xA0.w,xA1.w);                   \
    *reinterpret_cast<uint4*>(&sX[buf][rpA][4*c4]) = p_;                      \
    p_.x = packbf(xB0.x,xB1.x); p_.y = packbf(xB0.y,xB1.y);                   \
    p_.z = packbf(xB0.z,xB1.z); p_.w = packbf(xB0.w,xB1.w);                   \
    *reinterpret_cast<uint4*>(&sX[buf][rpB][4*c4]) = p_; }

#define UTX_MM(buf) {                                                         \
    _Pragma("unroll") for (int ksi = 0; ksi < 4; ++ksi) {                     \
        const int rp0_ = 8*ksi + 4*hi;                                        \
        UB a_, b_;                                                            \
        a_.q.x = sU[buf][rp0_+0][32*mq+lo];                                   \
        a_.q.y = sU[buf][rp0_+1][32*mq+lo];                                   \
        a_.q.z = sU[buf][rp0_+2][32*mq+lo];                                   \
        a_.q.w = sU[buf][rp0_+3][32*mq+lo];                                   \
        b_.q.x = sX[buf][rp0_+0][32*nq+lo];                                   \
        b_.q.y = sX[buf][rp0_+1][32*nq+lo];                                   \
        b_.q.z = sX[buf][rp0_+2][32*nq+lo];                                   \
        b_.q.w = sX[buf][rp0_+3][32*nq+lo];                                   \
        acc = __builtin_amdgcn_mfma_f32_32x32x16_bf16(a_.v, b_.v, acc, 0,0,0); } }

    f32x16 acc = {0};
    UTX_LD(0);
    UTX_WR(0);
    __syncthreads();
    #pragma unroll
    for (int t = 0; t < 8; ++t) {
        if (t < 7) UTX_LD(t+1);          // loads fly under compute
        UTX_MM(t & 1);
        if (t < 7) UTX_WR((t+1) & 1);    // write other buffer
        __syncthreads();
    }

    #pragma unroll
    for (int r = 0; r < 16; ++r) {
        const int mrow = mc0 + mq*32 + (r & 3) + 8*(r >> 2) + 4*hi;  // 0..255
        const int ncol = nc0 + nq*32 + lo;
        P[(ks*256 + mrow)*512 + ncol] = acc[r];
    }
#undef UTX_LD
#undef UTX_WR
#undef UTX_MM
}

// ---------------------------------------------------------------------------
// T[m][c] = sum_ks P[ks][m][c], m < 200.  grid 100.
// ---------------------------------------------------------------------------
__global__ __launch_bounds__(256) void k_red(
    const float* __restrict__ P, float* __restrict__ T)
{
    const int j  = blockIdx.x*256 + threadIdx.x;  // 0..25599
    const int m  = j >> 7;                        // row (128 f4 per row)
    const int c4 = j & 127;
    float4 s4 = {0.f, 0.f, 0.f, 0.f};
    for (int ks = 0; ks < 16; ++ks) {
        const float4 v = *reinterpret_cast<const float4*>(&P[(ks*256 + m)*512 + 4*c4]);
        s4.x += v.x; s4.y += v.y; s4.z += v.z; s4.w += v.w;
    }
    *reinterpret_cast<float4*>(&T[m*512 + 4*c4]) = s4;
}

// ---------------------------------------------------------------------------
// G = T @ Ww   [200][256] (unchanged)
// ---------------------------------------------------------------------------
__global__ __launch_bounds__(256) void k_g(
    const float* __restrict__ T, const float* __restrict__ Ww,
    float* __restrict__ G)
{
    const int k0  = blockIdx.x * 4;
    const int c   = threadIdx.x;
    __shared__ float4 sT4[4][128];

    for (int j = threadIdx.x; j < 512; j += 256) {
        const int r = j >> 7, c4 = j & 127;
        sT4[r][c4] = reinterpret_cast<const float4*>(T)[(k0+r)*128 + c4];
    }
    __syncthreads();

    float a0 = 0.f, a1 = 0.f, a2 = 0.f, a3 = 0.f;
    for (int ci4 = 0; ci4 < 128; ++ci4) {
        const float w0 = Ww[(4*ci4+0)*HID_ + c];
        const float w1 = Ww[(4*ci4+1)*HID_ + c];
        const float w2 = Ww[(4*ci4+2)*HID_ + c];
        const float w3 = Ww[(4*ci4+3)*HID_ + c];
        float4 t;
        t = sT4[0][ci4]; a0 += t.x*w0 + t.y*w1 + t.z*w2 + t.w*w3;
        t = sT4[1][ci4]; a1 += t.x*w0 + t.y*w1 + t.z*w2 + t.w*w3;
        t = sT4[2][ci4]; a2 += t.x*w0 + t.y*w1 + t.z*w2 + t.w*w3;
        t = sT4[3][ci4]; a3 += t.x*w0 + t.y*w1 + t.z*w2 + t.w*w3;
    }
    G[(k0+0)*HID_ + c] = a0;
    G[(k0+1)*HID_ + c] = a1;
    G[(k0+2)*HID_ + c] = a2;
    G[(k0+3)*HID_ + c] = a3;
}

// ---------------------------------------------------------------------------
// hidden = (U*s) @ G + Wb  via MFMA + fused BN stats (unchanged).
// ---------------------------------------------------------------------------
__global__ __launch_bounds__(256) void k_hidden(
    const float* __restrict__ U, const float* __restrict__ s,
    const float* __restrict__ G, const float* __restrict__ Wb,
    float* __restrict__ hid, float* __restrict__ bnsum)
{
    const int c0  = blockIdx.x * 32;
    const int n0  = blockIdx.y * 128;
    const int tid = threadIdx.x;
    const int w   = tid >> 6;
    const int l   = tid & 63;
    const int lo  = l & 31;
    const int hi  = l >> 5;

    __shared__ uint  sA[104][129];   // 53.7 KB: pairs of (U*s), rows=k-pair
    __shared__ uint  sB[104][33];    // 13.7 KB: pairs of G
    __shared__ float ss[208];

    if (tid < 208) ss[tid] = (tid < K_) ? s[tid] : 0.f;
    __syncthreads();

    // stage A: unit (m 0..127, kq 0..25): k-range 8kq..8kq+7 of node n0+m
    #pragma unroll
    for (int u = 0; u < 13; ++u) {
        const int j  = tid + u*256;
        const int m  = j & 127, kq = j >> 7;
        float4 a = {0,0,0,0}, b = {0,0,0,0};
        if (kq < 25) {
            a = *reinterpret_cast<const float4*>(&U[(n0+m)*K_ + 8*kq]);
            b = *reinterpret_cast<const float4*>(&U[(n0+m)*K_ + 8*kq + 4]);
            a.x *= ss[8*kq+0]; a.y *= ss[8*kq+1]; a.z *= ss[8*kq+2]; a.w *= ss[8*kq+3];
            b.x *= ss[8*kq+4]; b.y *= ss[8*kq+5]; b.z *= ss[8*kq+6]; b.w *= ss[8*kq+7];
        }
        sA[4*kq+0][m] = packbf(a.x, a.y);
        sA[4*kq+1][m] = packbf(a.z, a.w);
        sA[4*kq+2][m] = packbf(b.x, b.y);
        sA[4*kq+3][m] = packbf(b.z, b.w);
    }
    // stage B: unit (c 0..31, kq 0..25)
    for (int j = tid; j < 832; j += 256) {
        const int c = j & 31, kq = j >> 5;
        float g[8];
        #pragma unroll
        for (int i = 0; i < 8; ++i)
            g[i] = (kq < 25) ? G[(8*kq+i)*HID_ + c0 + c] : 0.f;
        sB[4*kq+0][c] = packbf(g[0], g[1]);
        sB[4*kq+1][c] = packbf(g[2], g[3]);
        sB[4*kq+2][c] = packbf(g[4], g[5]);
        sB[4*kq+3][c] = packbf(g[6], g[7]);
    }
    __syncthreads();

    f32x16 acc = {0};
    #pragma unroll
    for (int t = 0; t < 13; ++t) {
        const int rp0 = 8*t + 4*hi;
        UB a_, b_;
        a_.q.x = sA[rp0+0][32*w + lo];
        a_.q.y = sA[rp0+1][32*w + lo];
        a_.q.z = sA[rp0+2][32*w + lo];
        a_.q.w = sA[rp0+3][32*w + lo];
        b_.q.x = sB[rp0+0][lo];
        b_.q.y = sB[rp0+1][lo];
        b_.q.z = sB[rp0+2][lo];
        b_.q.w = sB[rp0+3][lo];
        acc = __builtin_amdgcn_mfma_f32_32x32x16_bf16(a_.v, b_.v, acc, 0, 0, 0);
    }

    const float wb = Wb[c0 + lo];
    float sm = 0.f, sq = 0.f;
    #pragma unroll
    for (int r = 0; r < 16; ++r) {
        const int row = 32*w + (r & 3) + 8*(r >> 2) + 4*hi;
        const float h = acc[r] + wb;
        hid[(n0+row)*HID_ + c0 + lo] = h;
        sm += h; sq += h*h;
    }
    sm += __shfl_xor(sm, 32); sq += __shfl_xor(sq, 32);
    if (hi == 0) {
        atomicAdd(&bnsum[c0 + lo],        sm);
        atomicAdd(&bnsum[HID_ + c0 + lo], sq);
    }
}

// ---------------------------------------------------------------------------
// logits = relu(BN(hidden)) @ Mw + Mb; out = log_softmax (unchanged)
// ---------------------------------------------------------------------------
__global__ __launch_bounds__(256) void k_logits(
    const float* __restrict__ hid, const float* __restrict__ bnsum,
    const float* __restrict__ gamma, const float* __restrict__ beta,
    const float* __restrict__ Mw, const float* __restrict__ Mb,
    float* __restrict__ outls)
{
    __shared__ float sc[HID_], sh[HID_], sMb[COUT_];
    __shared__ float sMw[HID_][COUT_];        // 40 KB
    __shared__ float sPart[8][32][41];        // 42 KB

    const int tid = threadIdx.x;
    const int r   = tid & 31;
    const int sl  = tid >> 5;

    {
        const float sm = bnsum[tid], sq = bnsum[HID_+tid];
        const float mu  = sm * (1.0f/N_);
        const float var = sq * (1.0f/N_) - mu*mu;
        const float a   = gamma[tid] * rsqrtf(var + EPS_);
        sc[tid] = a;
        sh[tid] = beta[tid] - mu*a;
    }
    for (int j = tid; j < HID_*COUT_/4; j += 256)
        reinterpret_cast<float4*>(&sMw[0][0])[j] = reinterpret_cast<const float4*>(Mw)[j];
    if (tid < COUT_) sMb[tid] = Mb[tid];
    __syncthreads();

    const int n  = blockIdx.x*32 + r;
    const int cb = sl * 32;
    float acc[COUT_];
    #pragma unroll
    for (int j = 0; j < COUT_; ++j) acc[j] = 0.f;

    const float4* hrow = reinterpret_cast<const float4*>(&hid[n*HID_ + cb]);
    #pragma unroll
    for (int c4 = 0; c4 < 8; ++c4) {
        const float4 h4 = hrow[c4];
        const float hv[4] = {h4.x, h4.y, h4.z, h4.w};
        #pragma unroll
        for (int q = 0; q < 4; ++q) {
            const int c = cb + 4*c4 + q;
            const float hn = fmaxf(hv[q]*sc[c] + sh[c], 0.f);
            #pragma unroll
            for (int j0 = 0; j0 < COUT_; j0 += 4) {
                const float4 wv = *reinterpret_cast<const float4*>(&sMw[c][j0]);
                acc[j0+0] += hn*wv.x; acc[j0+1] += hn*wv.y;
                acc[j0+2] += hn*wv.z; acc[j0+3] += hn*wv.w;
            }
        }
    }
    #pragma unroll
    for (int j = 0; j < COUT_; ++j) sPart[sl][r][j] = acc[j];
    __syncthreads();

    if (tid < 32) {
        const int n2 = blockIdx.x*32 + tid;
        float a2[COUT_];
        #pragma unroll
        for (int j = 0; j < COUT_; ++j) {
            float sum = sMb[j];
            #pragma unroll
            for (int s2 = 0; s2 < 8; ++s2) sum += sPart[s2][tid][j];
            a2[j] = sum;
        }
        float m = -1e30f;
        #pragma unroll
        for (int j = 0; j < COUT_; ++j) m = fmaxf(m, a2[j]);
        float ssum = 0.f;
        #pragma unroll
        for (int j = 0; j < COUT_; ++j) ssum += expf(a2[j] - m);
        const float lse = m + logf(ssum);
        #pragma unroll
        for (int j = 0; j < COUT_; ++j)
            outls[n2*COUT_ + j] = a2[j] - lse;
    }
}

// ---------------------------------------------------------------------------
extern "C" void kernel_launch(void* const* d_in, const int* in_sizes, int n_in,
                              void* d_out, int out_size, void* d_ws, size_t ws_size,
                              hipStream_t stream)
{
    const float* X        = (const float*)d_in[0];
    const float* La       = (const float*)d_in[1];
    const float* U        = (const float*)d_in[2];
    const float* eW1      = (const float*)d_in[3];
    const float* eb1      = (const float*)d_in[4];
    const float* eW2      = (const float*)d_in[5];
    const float* eb2      = (const float*)d_in[6];
    const float* eW3      = (const float*)d_in[7];
    const float* eb3      = (const float*)d_in[8];
    const float* gW1      = (const float*)d_in[9];
    const float* gb1      = (const float*)d_in[10];
    const float* gW2      = (const float*)d_in[11];
    const float* gb2      = (const float*)d_in[12];
    const float* Ww       = (const float*)d_in[13];
    const float* Wb       = (const float*)d_in[14];
    const float* bn_gamma = (const float*)d_in[15];
    const float* bn_beta  = (const float*)d_in[16];
    const float* Mw       = (const float*)d_in[17];
    const float* Mb       = (const float*)d_in[18];

    float* out   = (float*)d_out;
    float* ws    = (float*)d_ws;
    float* Vsum  = ws + WS_VSUM;
    float* bnsum = ws + WS_BNSUM;
    float* T     = ws + WS_T;
    float* s     = ws + WS_S;
    float* G     = ws + WS_G;

    float* outls = out;                 // [8192][40] log_softmax (written last)
    float* hid   = out + N_*COUT_;      // [8192][256] hidden (output 1)
    float* P     = out;                 // k_utx partials: 16*256*512*4 = 8.4 MB
                                        // in d_out scratch, consumed by k_red
                                        // before k_hidden overwrites hid.

    // zero Vsum + bnsum (atomic accumulators); T written fully by k_red.
    (void)hipMemsetAsync(ws, 0, (size_t)768 * sizeof(float), stream);

    k_utx   <<<dim3(8, 4, 16), 256, 0, stream>>>(U, X, P);
    k_expert<<<dim3(E_, 640),  256, 0, stream>>>(U, eW1, eb1, eW2, eb2, eW3, eb3, Vsum);
    k_gate  <<<1,   256, 0, stream>>>(La, gW1, gb1, gW2, gb2, Vsum, s);
    k_red   <<<100, 256, 0, stream>>>(P, T);
    k_g     <<<50,  256, 0, stream>>>(T, Ww, G);
    k_hidden<<<dim3(8, 64), 256, 0, stream>>>(U, s, G, Wb, hid, bnsum);
    k_logits<<<256, 256, 0, stream>>>(hid, bnsum, bn_gamma, bn_beta, Mw, Mb, outls);
}

// Round 10
// 201.348 us; speedup vs baseline: 1.1329x; 1.0463x over previous
//
#include <hip/hip_runtime.h>
#include <hip/hip_bf16.h>

// Problem constants
#define N_    8192
#define K_    200
#define CIN_  512
#define HID_  256
#define COUT_ 40
#define E_    5
#define MH_   64
#define KG_   40
#define EPS_  1e-5f

// Workspace layout (floats):
#define WS_VSUM  0
#define WS_BNSUM 256
#define WS_S     103168
#define WS_G     103424

typedef __bf16 bf16x8 __attribute__((ext_vector_type(8)));
typedef _Float16 f16x2 __attribute__((ext_vector_type(2)));
typedef _Float16 f16x8 __attribute__((ext_vector_type(8)));
typedef float  f32x16 __attribute__((ext_vector_type(16)));

__device__ __forceinline__ uint packbf(float a, float b) {
    union { __bf16 h[2]; uint u; } p;
    p.h[0] = (__bf16)a; p.h[1] = (__bf16)b;
    return p.u;
}

union UB { uint4 q; bf16x8 v; };
union UHF { f16x2 h2[4]; f16x8 v; };

// ---------------------------------------------------------------------------
// K1: fused k_utx (blocks 0..511) + k_expert (blocks 512..3711).
// Both paths are the verified round-8/9 bodies, unchanged math; they share
// one LDS arena (utx: 34.8 KB double-buffered staging; expert: 1.5 KB).
// utx:   P[ks] partials of U^T X, 64x64 tiles, 2-phase pipelined.
// expert: tiny-MLP via f16 MFMA, 32-col tiles, b2 via MFMA C-in.
// ---------------------------------------------------------------------------
__global__ __launch_bounds__(256) void k_fused1(
    const float* __restrict__ U, const float* __restrict__ X,
    float* __restrict__ P,
    const float* __restrict__ eW1, const float* __restrict__ eb1,
    const float* __restrict__ eW2, const float* __restrict__ eb2,
    const float* __restrict__ eW3, const float* __restrict__ eb3,
    float* __restrict__ Vsum)
{
    __shared__ __align__(16) char ldsraw[34816];
    const int tid = threadIdx.x;
    const int w   = tid >> 6;
    const int l   = tid & 63;
    const int lo  = l & 31;
    const int hi  = l >> 5;

    if (blockIdx.x < 512) {
        // ================= UTX path =================
        const int bid = blockIdx.x;
        const int nc0 = (bid & 7) * 64;
        const int mc0 = ((bid >> 3) & 3) * 64;
        const int ks  = bid >> 5;
        const int r0  = ks * 512;
        const int mq  = w >> 1, nq = w & 1;

        typedef uint UtxBuf[32][68];
        UtxBuf* sU = reinterpret_cast<UtxBuf*>(ldsraw);                 // [2][32][68]
        UtxBuf* sX = reinterpret_cast<UtxBuf*>(ldsraw + 17408);        // [2][32][68]

        const int rpA = tid >> 4;        // 0..15
        const int rpB = rpA + 16;
        const int c4  = tid & 15;
        const int mcA = mc0 + 4*c4;      // may exceed 199 -> clamp addr
        const int xcA = nc0 + 4*c4;
        const int UMAX = N_*K_ - 4;

        float4 uA0,uA1,uB0,uB1,xA0,xA1,xB0,xB1;

#define UTX_LD(chunk) {                                                       \
    const int rb_ = r0 + 64*(chunk);                                          \
    uA0 = *reinterpret_cast<const float4*>(&U[min((rb_+2*rpA  )*K_ + mcA, UMAX)]); \
    uA1 = *reinterpret_cast<const float4*>(&U[min((rb_+2*rpA+1)*K_ + mcA, UMAX)]); \
    uB0 = *reinterpret_cast<const float4*>(&U[min((rb_+2*rpB  )*K_ + mcA, UMAX)]); \
    uB1 = *reinterpret_cast<const float4*>(&U[min((rb_+2*rpB+1)*K_ + mcA, UMAX)]); \
    xA0 = *reinterpret_cast<const float4*>(&X[(rb_+2*rpA  )*CIN_ + xcA]);     \
    xA1 = *reinterpret_cast<const float4*>(&X[(rb_+2*rpA+1)*CIN_ + xcA]);     \
    xB0 = *reinterpret_cast<const float4*>(&X[(rb_+2*rpB  )*CIN_ + xcA]);     \
    xB1 = *reinterpret_cast<const float4*>(&X[(rb_+2*rpB+1)*CIN_ + xcA]); }

#define UTX_WR(buf) {                                                         \
    uint4 p_;                                                                 \
    p_.x = packbf(uA0.x,uA1.x); p_.y = packbf(uA0.y,uA1.y);                   \
    p_.z = packbf(uA0.z,uA1.z); p_.w = packbf(uA0.w,uA1.w);                   \
    *reinterpret_cast<uint4*>(&sU[buf][rpA][4*c4]) = p_;                      \
    p_.x = packbf(uB0.x,uB1.x); p_.y = packbf(uB0.y,uB1.y);                   \
    p_.z = packbf(uB0.z,uB1.z); p_.w = packbf(uB0.w,uB1.w);                   \
    *reinterpret_cast<uint4*>(&sU[buf][rpB][4*c4]) = p_;                      \
    p_.x = packbf(xA0.x,xA1.x); p_.y = packbf(xA0.y,xA1.y);                   \
    p_.z = packbf(xA0.z,xA1.z); p_.w = packbf(xA0.w,xA1.w);                   \
    *reinterpret_cast<uint4*>(&sX[buf][rpA][4*c4]) = p_;                      \
    p_.x = packbf(xB0.x,xB1.x); p_.y = packbf(xB0.y,xB1.y);                   \
    p_.z = packbf(xB0.z,xB1.z); p_.w = packbf(xB0.w,xB1.w);                   \
    *reinterpret_cast<uint4*>(&sX[buf][rpB][4*c4]) = p_; }

#define UTX_MM(buf) {                                                         \
    _Pragma("unroll") for (int ksi = 0; ksi < 4; ++ksi) {                     \
        const int rp0_ = 8*ksi + 4*hi;                                        \
        UB a_, b_;                                                            \
        a_.q.x = sU[buf][rp0_+0][32*mq+lo];                                   \
        a_.q.y = sU[buf][rp0_+1][32*mq+lo];                                   \
        a_.q.z = sU[buf][rp0_+2][32*mq+lo];                                   \
        a_.q.w = sU[buf][rp0_+3][32*mq+lo];                                   \
        b_.q.x = sX[buf][rp0_+0][32*nq+lo];                                   \
        b_.q.y = sX[buf][rp0_+1][32*nq+lo];                                   \
        b_.q.z = sX[buf][rp0_+2][32*nq+lo];                                   \
        b_.q.w = sX[buf][rp0_+3][32*nq+lo];                                   \
        acc = __builtin_amdgcn_mfma_f32_32x32x16_bf16(a_.v, b_.v, acc, 0,0,0); } }

        f32x16 acc = {0};
        UTX_LD(0);
        UTX_WR(0);
        __syncthreads();
        #pragma unroll
        for (int t = 0; t < 8; ++t) {
            if (t < 7) UTX_LD(t+1);
            UTX_MM(t & 1);
            if (t < 7) UTX_WR((t+1) & 1);
            __syncthreads();
        }

        #pragma unroll
        for (int r = 0; r < 16; ++r) {
            const int mrow = mc0 + mq*32 + (r & 3) + 8*(r >> 2) + 4*hi;  // 0..255
            const int ncol = nc0 + nq*32 + lo;
            P[(ks*256 + mrow)*512 + ncol] = acc[r];
        }
#undef UTX_LD
#undef UTX_WR
#undef UTX_MM
        return;
    }

    // ================= EXPERT path =================
    {
        const int t5 = blockIdx.x - 512;
        const int e  = t5 % E_;
        const int by = t5 / E_;

        struct ExLds {
            f16x2 sW1h[32]; f16x2 sb1h[32];
            float sb2s[MH_]; float sW3s[MH_];
            float colsum[4][48];
        };
        ExLds& S = *reinterpret_cast<ExLds*>(ldsraw);

        if (tid < 32) {
            f16x2 w2; w2.x = (_Float16)eW1[e*MH_ + 2*tid]; w2.y = (_Float16)eW1[e*MH_ + 2*tid + 1];
            S.sW1h[tid] = w2;
            f16x2 b2; b2.x = (_Float16)eb1[e*MH_ + 2*tid]; b2.y = (_Float16)eb1[e*MH_ + 2*tid + 1];
            S.sb1h[tid] = b2;
        }
        if (tid < MH_) {
            S.sb2s[tid] = eb2[e*MH_ + tid];
            S.sW3s[tid] = eW3[e*MH_ + tid];
        }
        if (tid < 192) S.colsum[tid / 48][tid % 48] = 0.f;
        const float b3 = eb3[e];

        UHF fa[2][4];
        {
            const float* W2e = eW2 + e*MH_*MH_;
            #pragma unroll
            for (int mt = 0; mt < 2; ++mt) {
                const int grow = mt*32 + lo;
                #pragma unroll
                for (int t = 0; t < 4; ++t) {
                    const int k0 = 16*t + 8*hi;
                    #pragma unroll
                    for (int r = 0; r < 4; ++r) {
                        f16x2 p;
                        p.x = (_Float16)W2e[(k0+2*r  )*MH_ + grow];
                        p.y = (_Float16)W2e[(k0+2*r+1)*MH_ + grow];
                        fa[mt][t].h2[r] = p;
                    }
                }
            }
        }
        __syncthreads();

        f32x16 ci0, ci1;
        #pragma unroll
        for (int r = 0; r < 16; ++r) {
            const int gb = (r & 3) + 8*(r >> 2) + 4*hi;
            ci0[r] = S.sb2s[gb];
            ci1[r] = S.sb2s[32 + gb];
        }

        float uu[4]; int kgs[4];
        const int tile0 = by*16 + w*4;
        #pragma unroll
        for (int it = 0; it < 4; ++it) {
            const int idx = (tile0 + it)*32 + lo;
            const int n   = idx / KG_;
            const int kg  = idx - n*KG_;
            uu[it]  = U[n*K_ + e*KG_ + kg];
            kgs[it] = kg;
        }

        const f16x2 z2 = {(_Float16)0.f, (_Float16)0.f};

        #pragma unroll
        for (int it = 0; it < 4; ++it) {
            f16x2 u2; u2.x = (_Float16)uu[it]; u2.y = u2.x;

            f32x16 a0, a1;
            #pragma unroll
            for (int t = 0; t < 4; ++t) {
                const int kp = 8*t + 4*hi;
                UHF b;
                #pragma unroll
                for (int r = 0; r < 4; ++r)
                    b.h2[r] = __builtin_elementwise_max(u2*S.sW1h[kp + r] + S.sb1h[kp + r], z2);
                if (t == 0) {
                    a0 = __builtin_amdgcn_mfma_f32_32x32x16_f16(fa[0][0].v, b.v, ci0, 0, 0, 0);
                    a1 = __builtin_amdgcn_mfma_f32_32x32x16_f16(fa[1][0].v, b.v, ci1, 0, 0, 0);
                } else {
                    a0 = __builtin_amdgcn_mfma_f32_32x32x16_f16(fa[0][t].v, b.v, a0, 0, 0, 0);
                    a1 = __builtin_amdgcn_mfma_f32_32x32x16_f16(fa[1][t].v, b.v, a1, 0, 0, 0);
                }
            }

            float p0 = 0.f, p1 = 0.f, p2 = 0.f, p3 = 0.f;
            #pragma unroll
            for (int r = 0; r < 16; r += 2) {
                const int g0 = (r & 3) + 8*(r >> 2) + 4*hi;
                const int g1 = ((r+1) & 3) + 8*((r+1) >> 2) + 4*hi;
                p0 += fmaxf(a0[r],   0.f) * S.sW3s[g0];
                p1 += fmaxf(a1[r],   0.f) * S.sW3s[32 + g0];
                p2 += fmaxf(a0[r+1], 0.f) * S.sW3s[g1];
                p3 += fmaxf(a1[r+1], 0.f) * S.sW3s[32 + g1];
            }
            float vs = (p0 + p1) + (p2 + p3);
            vs += __shfl_xor(vs, 32);
            if (hi == 0) atomicAdd(&S.colsum[w][kgs[it]], vs + b3);
        }

        __syncthreads();
        if (tid < KG_)
            atomicAdd(&Vsum[e*KG_ + tid],
                      S.colsum[0][tid] + S.colsum[1][tid] + S.colsum[2][tid] + S.colsum[3][tid]);
    }
}

// ---------------------------------------------------------------------------
// K2: fused k_red + k_g + k_gate.  Blocks 0..49: reduce own 4 T-rows from P
// into LDS, then G rows = T@Ww.  Block 50: gate -> s.
// ---------------------------------------------------------------------------
__global__ __launch_bounds__(256) void k_rgg(
    const float* __restrict__ P, const float* __restrict__ Ww,
    const float* __restrict__ La,
    const float* __restrict__ gW1, const float* __restrict__ gb1,
    const float* __restrict__ gW2, const float* __restrict__ gb2,
    const float* __restrict__ Vsum,
    float* __restrict__ s, float* __restrict__ G)
{
    const int tid = threadIdx.x;

    if (blockIdx.x == 50) {
        __shared__ float sg[E_];
        if (tid == 0) {
            float stats[E_], g1[E_], g2[E_];
            for (int e = 0; e < E_; ++e) {
                float acc = 0.f;
                for (int k = 0; k < KG_; ++k) acc += La[e*KG_ + k];
                stats[e] = acc * (1.0f/KG_);
            }
            for (int j = 0; j < E_; ++j) {
                float acc = gb1[j];
                for (int i = 0; i < E_; ++i) acc += stats[i]*gW1[i*E_ + j];
                g1[j] = fmaxf(acc, 0.f);
            }
            float m = -1e30f;
            for (int j = 0; j < E_; ++j) {
                float acc = gb2[j];
                for (int i = 0; i < E_; ++i) acc += g1[i]*gW2[i*E_ + j];
                g2[j] = acc;
                m = fmaxf(m, acc);
            }
            float ssum = 0.f;
            for (int j = 0; j < E_; ++j) { g2[j] = expf(g2[j]-m); ssum += g2[j]; }
            for (int j = 0; j < E_; ++j) sg[j] = g2[j] / ssum;
        }
        __syncthreads();
        if (tid < K_) s[tid] = sg[tid / KG_] * Vsum[tid] * (1.0f/N_);
        return;
    }

    __shared__ float4 sT4[4][128];
    const int k0 = blockIdx.x * 4;

    for (int j = tid; j < 512; j += 256) {
        const int r = j >> 7, c4 = j & 127;
        float4 a = {0.f, 0.f, 0.f, 0.f};
        for (int ks = 0; ks < 16; ++ks) {
            const float4 v = *reinterpret_cast<const float4*>(&P[(ks*256 + k0 + r)*512 + 4*c4]);
            a.x += v.x; a.y += v.y; a.z += v.z; a.w += v.w;
        }
        sT4[r][c4] = a;
    }
    __syncthreads();

    const int c = tid;
    float a0 = 0.f, a1 = 0.f, a2 = 0.f, a3 = 0.f;
    for (int ci4 = 0; ci4 < 128; ++ci4) {
        const float w0 = Ww[(4*ci4+0)*HID_ + c];
        const float w1 = Ww[(4*ci4+1)*HID_ + c];
        const float w2 = Ww[(4*ci4+2)*HID_ + c];
        const float w3 = Ww[(4*ci4+3)*HID_ + c];
        float4 t;
        t = sT4[0][ci4]; a0 += t.x*w0 + t.y*w1 + t.z*w2 + t.w*w3;
        t = sT4[1][ci4]; a1 += t.x*w0 + t.y*w1 + t.z*w2 + t.w*w3;
        t = sT4[2][ci4]; a2 += t.x*w0 + t.y*w1 + t.z*w2 + t.w*w3;
        t = sT4[3][ci4]; a3 += t.x*w0 + t.y*w1 + t.z*w2 + t.w*w3;
    }
    G[(k0+0)*HID_ + c] = a0;
    G[(k0+1)*HID_ + c] = a1;
    G[(k0+2)*HID_ + c] = a2;
    G[(k0+3)*HID_ + c] = a3;
}

// ---------------------------------------------------------------------------
// hidden = (U*s) @ G + Wb  via MFMA + fused BN stats (unchanged).
// ---------------------------------------------------------------------------
__global__ __launch_bounds__(256) void k_hidden(
    const float* __restrict__ U, const float* __restrict__ s,
    const float* __restrict__ G, const float* __restrict__ Wb,
    float* __restrict__ hid, float* __restrict__ bnsum)
{
    const int c0  = blockIdx.x * 32;
    const int n0  = blockIdx.y * 128;
    const int tid = threadIdx.x;
    const int w   = tid >> 6;
    const int l   = tid & 63;
    const int lo  = l & 31;
    const int hi  = l >> 5;

    __shared__ uint  sA[104][129];   // 53.7 KB
    __shared__ uint  sB[104][33];    // 13.7 KB
    __shared__ float ss[208];

    if (tid < 208) ss[tid] = (tid < K_) ? s[tid] : 0.f;
    __syncthreads();

    #pragma unroll
    for (int u = 0; u < 13; ++u) {
        const int j  = tid + u*256;
        const int m  = j & 127, kq = j >> 7;
        float4 a = {0,0,0,0}, b = {0,0,0,0};
        if (kq < 25) {
            a = *reinterpret_cast<const float4*>(&U[(n0+m)*K_ + 8*kq]);
            b = *reinterpret_cast<const float4*>(&U[(n0+m)*K_ + 8*kq + 4]);
            a.x *= ss[8*kq+0]; a.y *= ss[8*kq+1]; a.z *= ss[8*kq+2]; a.w *= ss[8*kq+3];
            b.x *= ss[8*kq+4]; b.y *= ss[8*kq+5]; b.z *= ss[8*kq+6]; b.w *= ss[8*kq+7];
        }
        sA[4*kq+0][m] = packbf(a.x, a.y);
        sA[4*kq+1][m] = packbf(a.z, a.w);
        sA[4*kq+2][m] = packbf(b.x, b.y);
        sA[4*kq+3][m] = packbf(b.z, b.w);
    }
    for (int j = tid; j < 832; j += 256) {
        const int c = j & 31, kq = j >> 5;
        float g[8];
        #pragma unroll
        for (int i = 0; i < 8; ++i)
            g[i] = (kq < 25) ? G[(8*kq+i)*HID_ + c0 + c] : 0.f;
        sB[4*kq+0][c] = packbf(g[0], g[1]);
        sB[4*kq+1][c] = packbf(g[2], g[3]);
        sB[4*kq+2][c] = packbf(g[4], g[5]);
        sB[4*kq+3][c] = packbf(g[6], g[7]);
    }
    __syncthreads();

    f32x16 acc = {0};
    #pragma unroll
    for (int t = 0; t < 13; ++t) {
        const int rp0 = 8*t + 4*hi;
        UB a_, b_;
        a_.q.x = sA[rp0+0][32*w + lo];
        a_.q.y = sA[rp0+1][32*w + lo];
        a_.q.z = sA[rp0+2][32*w + lo];
        a_.q.w = sA[rp0+3][32*w + lo];
        b_.q.x = sB[rp0+0][lo];
        b_.q.y = sB[rp0+1][lo];
        b_.q.z = sB[rp0+2][lo];
        b_.q.w = sB[rp0+3][lo];
        acc = __builtin_amdgcn_mfma_f32_32x32x16_bf16(a_.v, b_.v, acc, 0, 0, 0);
    }

    const float wb = Wb[c0 + lo];
    float sm = 0.f, sq = 0.f;
    #pragma unroll
    for (int r = 0; r < 16; ++r) {
        const int row = 32*w + (r & 3) + 8*(r >> 2) + 4*hi;
        const float h = acc[r] + wb;
        hid[(n0+row)*HID_ + c0 + lo] = h;
        sm += h; sq += h*h;
    }
    sm += __shfl_xor(sm, 32); sq += __shfl_xor(sq, 32);
    if (hi == 0) {
        atomicAdd(&bnsum[c0 + lo],        sm);
        atomicAdd(&bnsum[HID_ + c0 + lo], sq);
    }
}

// ---------------------------------------------------------------------------
// logits = relu(BN(hidden)) @ Mw + Mb; out = log_softmax (unchanged)
// ---------------------------------------------------------------------------
__global__ __launch_bounds__(256) void k_logits(
    const float* __restrict__ hid, const float* __restrict__ bnsum,
    const float* __restrict__ gamma, const float* __restrict__ beta,
    const float* __restrict__ Mw, const float* __restrict__ Mb,
    float* __restrict__ outls)
{
    __shared__ float sc[HID_], sh[HID_], sMb[COUT_];
    __shared__ float sMw[HID_][COUT_];        // 40 KB
    __shared__ float sPart[8][32][41];        // 42 KB

    const int tid = threadIdx.x;
    const int r   = tid & 31;
    const int sl  = tid >> 5;

    {
        const float sm = bnsum[tid], sq = bnsum[HID_+tid];
        const float mu  = sm * (1.0f/N_);
        const float var = sq * (1.0f/N_) - mu*mu;
        const float a   = gamma[tid] * rsqrtf(var + EPS_);
        sc[tid] = a;
        sh[tid] = beta[tid] - mu*a;
    }
    for (int j = tid; j < HID_*COUT_/4; j += 256)
        reinterpret_cast<float4*>(&sMw[0][0])[j] = reinterpret_cast<const float4*>(Mw)[j];
    if (tid < COUT_) sMb[tid] = Mb[tid];
    __syncthreads();

    const int n  = blockIdx.x*32 + r;
    const int cb = sl * 32;
    float acc[COUT_];
    #pragma unroll
    for (int j = 0; j < COUT_; ++j) acc[j] = 0.f;

    const float4* hrow = reinterpret_cast<const float4*>(&hid[n*HID_ + cb]);
    #pragma unroll
    for (int c4 = 0; c4 < 8; ++c4) {
        const float4 h4 = hrow[c4];
        const float hv[4] = {h4.x, h4.y, h4.z, h4.w};
        #pragma unroll
        for (int q = 0; q < 4; ++q) {
            const int c = cb + 4*c4 + q;
            const float hn = fmaxf(hv[q]*sc[c] + sh[c], 0.f);
            #pragma unroll
            for (int j0 = 0; j0 < COUT_; j0 += 4) {
                const float4 wv = *reinterpret_cast<const float4*>(&sMw[c][j0]);
                acc[j0+0] += hn*wv.x; acc[j0+1] += hn*wv.y;
                acc[j0+2] += hn*wv.z; acc[j0+3] += hn*wv.w;
            }
        }
    }
    #pragma unroll
    for (int j = 0; j < COUT_; ++j) sPart[sl][r][j] = acc[j];
    __syncthreads();

    if (tid < 32) {
        const int n2 = blockIdx.x*32 + tid;
        float a2[COUT_];
        #pragma unroll
        for (int j = 0; j < COUT_; ++j) {
            float sum = sMb[j];
            #pragma unroll
            for (int s2 = 0; s2 < 8; ++s2) sum += sPart[s2][tid][j];
            a2[j] = sum;
        }
        float m = -1e30f;
        #pragma unroll
        for (int j = 0; j < COUT_; ++j) m = fmaxf(m, a2[j]);
        float ssum = 0.f;
        #pragma unroll
        for (int j = 0; j < COUT_; ++j) ssum += expf(a2[j] - m);
        const float lse = m + logf(ssum);
        #pragma unroll
        for (int j = 0; j < COUT_; ++j)
            outls[n2*COUT_ + j] = a2[j] - lse;
    }
}

// ---------------------------------------------------------------------------
extern "C" void kernel_launch(void* const* d_in, const int* in_sizes, int n_in,
                              void* d_out, int out_size, void* d_ws, size_t ws_size,
                              hipStream_t stream)
{
    const float* X        = (const float*)d_in[0];
    const float* La       = (const float*)d_in[1];
    const float* U        = (const float*)d_in[2];
    const float* eW1      = (const float*)d_in[3];
    const float* eb1      = (const float*)d_in[4];
    const float* eW2      = (const float*)d_in[5];
    const float* eb2      = (const float*)d_in[6];
    const float* eW3      = (const float*)d_in[7];
    const float* eb3      = (const float*)d_in[8];
    const float* gW1      = (const float*)d_in[9];
    const float* gb1      = (const float*)d_in[10];
    const float* gW2      = (const float*)d_in[11];
    const float* gb2      = (const float*)d_in[12];
    const float* Ww       = (const float*)d_in[13];
    const float* Wb       = (const float*)d_in[14];
    const float* bn_gamma = (const float*)d_in[15];
    const float* bn_beta  = (const float*)d_in[16];
    const float* Mw       = (const float*)d_in[17];
    const float* Mb       = (const float*)d_in[18];

    float* out   = (float*)d_out;
    float* ws    = (float*)d_ws;
    float* Vsum  = ws + WS_VSUM;
    float* bnsum = ws + WS_BNSUM;
    float* s     = ws + WS_S;
    float* G     = ws + WS_G;

    float* outls = out;                 // [8192][40] log_softmax (written last)
    float* hid   = out + N_*COUT_;      // [8192][256] hidden (output 1)
    float* P     = out;                 // k_utx partials: 16*256*512*4 = 8.4 MB
                                        // in d_out scratch, consumed by k_rgg
                                        // before k_hidden overwrites hid.

    // zero Vsum + bnsum (atomic accumulators)
    (void)hipMemsetAsync(ws, 0, (size_t)768 * sizeof(float), stream);

    k_fused1<<<3712, 256, 0, stream>>>(U, X, P, eW1, eb1, eW2, eb2, eW3, eb3, Vsum);
    k_rgg   <<<51,   256, 0, stream>>>(P, Ww, La, gW1, gb1, gW2, gb2, Vsum, s, G);
    k_hidden<<<dim3(8, 64), 256, 0, stream>>>(U, s, G, Wb, hid, bnsum);
    k_logits<<<256,  256, 0, stream>>>(hid, bnsum, bn_gamma, bn_beta, Mw, Mb, outls);
}